// Round 5
// baseline (335.335 us; speedup 1.0000x reference)
//
#include <hip/hip_runtime.h>
#include <hip/hip_bf16.h>

typedef __bf16 bf16x8 __attribute__((ext_vector_type(8)));
typedef float f32x4 __attribute__((ext_vector_type(4)));

#define NB 4
#define NC 256
#define NN 4096
#define BK 32
#define NT 64   // tiles per j-group: 2 groups * 64 tiles * BK = 4096

__device__ __forceinline__ void stage16(const void* g, void* l) {
    __builtin_amdgcn_global_load_lds(
        (const __attribute__((address_space(1))) unsigned int*)g,
        (__attribute__((address_space(3))) unsigned int*)l, 16, 0, 0);
}

// ---------- prep: x fp32 [b][c][n] -> xt bf16 [b][n][c] (transposed), xc bf16 [b][c][n] ----------
__global__ __launch_bounds__(256) void prep_kernel(const float* __restrict__ x,
                                                   __bf16* __restrict__ xt,
                                                   __bf16* __restrict__ xc) {
    __shared__ __align__(16) __bf16 tile[64 * 64];  // swizzled 16B chunks, no pad
    const int b = blockIdx.z, c0 = blockIdx.y * 64, n0 = blockIdx.x * 64;
    const int t = threadIdx.x;
    {
        const int cc = t >> 2, nch = (t & 3) << 4;   // 16 floats per thread
        const float* src = x + ((size_t)(b * NC + c0 + cc)) * NN + n0 + nch;
        f32x4 v[4];
        v[0] = *(const f32x4*)(src);
        v[1] = *(const f32x4*)(src + 4);
        v[2] = *(const f32x4*)(src + 8);
        v[3] = *(const f32x4*)(src + 12);
        bf16x8 o[2];
#pragma unroll
        for (int q = 0; q < 2; ++q)
#pragma unroll
            for (int k = 0; k < 8; ++k)
                o[q][k] = (__bf16)v[q * 2 + (k >> 2)][k & 3];
        __bf16* dst = xc + ((size_t)(b * NC + c0 + cc)) * NN + n0 + nch;
        *(bf16x8*)(dst) = o[0];
        *(bf16x8*)(dst + 8) = o[1];
        const int key = (cc ^ (cc >> 3)) & 7;        // rows 16 apart get distinct keys
#pragma unroll
        for (int q = 0; q < 2; ++q) {
            int nc = (nch >> 3) + q;
            *(bf16x8*)(&tile[cc * 64 + ((nc ^ key) << 3)]) = o[q];
        }
    }
    __syncthreads();
    {
        const int nn = t >> 2, cch = (t & 3) << 4;
        bf16x8 o[2];
#pragma unroll
        for (int k = 0; k < 16; ++k) {
            int r = cch + k;
            int key = (r ^ (r >> 3)) & 7;
            o[k >> 3][k & 7] = tile[r * 64 + (((nn >> 3) ^ key) << 3) + (nn & 7)];
        }
        __bf16* dst = xt + ((size_t)(b * NN + n0 + nn)) * NC + c0 + cch;
        *(bf16x8*)(dst) = o[0];
        *(bf16x8*)(dst + 8) = o[1];
    }
}

// ---------- flash attention: 512 blocks (2/CU), 4 waves = 2 KV-groups x 2 q-strips ----------
__global__ __launch_bounds__(256, 2) void flash_kernel(const __bf16* __restrict__ xt,
                                                       const __bf16* __restrict__ xc,
                                                       float* __restrict__ out) {
    __shared__ __align__(16) __bf16 sK[2][2][BK * NC];  // [group][buf][32 j][256 c] 64KB
    __shared__ __align__(16) __bf16 sP[4][16 * BK];     // per-wave P strip, 4KB
    __shared__ float sML[4][16][2];                     // m,l exchange

    const int bid = blockIdx.x;
    const int xcd = bid & 7;
    const int b = xcd >> 1;                          // batch -> XCD pair; 4MB/batch = L2/XCD
    const int qblk = ((bid >> 3) << 1) | (xcd & 1);  // 0..127

    const int tid = threadIdx.x;
    const int w = tid >> 6;        // wave 0..3
    const int grp = w >> 1;        // 0: tiles 0..63, 1: tiles 64..127
    const int wg = w & 1;          // q-strip
    const int lane = tid & 63;
    const int l16 = lane & 15;
    const int gq = lane >> 4;

    const int i_base = qblk * 32 + wg * 16;

    const char* xtb = (const char*)(xt + (size_t)b * NN * NC);
    const __bf16* vbase = xc + (size_t)b * NC * NN;

    // Q fragments in registers: A[i=l16][k = gq*8+e + 32*ck]
    bf16x8 qf[8];
    {
        const __bf16* qrow = (const __bf16*)xtb + (size_t)(i_base + l16) * NC + gq * 8;
#pragma unroll
        for (int ck = 0; ck < 8; ++ck) qf[ck] = *(const bf16x8*)(qrow + ck * 32);
    }

    f32x4 acc[16];
#pragma unroll
    for (int cf = 0; cf < 16; ++cf) acc[cf] = (f32x4){0.f, 0.f, 0.f, 0.f};
    float m_run[4], l_run[4];
#pragma unroll
    for (int r = 0; r < 4; ++r) { m_run[r] = -3.0e38f; l_run[r] = 0.f; }

    // stage K tile t of this wave's group into buffer bf (linear LDS dest,
    // swizzle applied by permuting the GLOBAL source chunk - rule #21)
    auto stage = [&](int bf, int t) {
        const int tj = grp * NT + t;
        const char* kb = xtb + (size_t)tj * BK * (NC * 2);
        __bf16* dk = &sK[grp][bf][0];
#pragma unroll
        for (int q = 0; q < 8; ++q) {
            int ci = wg * 8 + q;                 // 1KB chunk = 2 K-rows
            int rl = ci * 2 + (lane >> 5);
            int cs = (lane & 31) ^ (rl & 7);     // inverse of read swizzle
            stage16(kb + rl * 512 + cs * 16, dk + ci * 512);
        }
    };

    stage(0, 0);
    __syncthreads();
    int cur = 0;

    const __bf16* vrow = vbase + (size_t)l16 * NN + gq * 8;

    for (int t = 0; t < NT; ++t) {
        if (t + 1 < NT) stage(cur ^ 1, t + 1);   // issue-early; drains at the barrier below

        const int j0 = (grp * NT + t) * BK;

        // V fragments straight from global (L1/L2-resident; consumed ~800cy later)
        bf16x8 vv[16];
#pragma unroll
        for (int cf = 0; cf < 16; ++cf)
            vv[cf] = *(const bf16x8*)(vrow + (size_t)cf * 16 * NN + j0);

        const __bf16* kt = &sK[grp][cur][0];

        // S = Q K^T  (two 16-col fragments cover BK=32)
        f32x4 s0 = (f32x4){0.f, 0.f, 0.f, 0.f};
        f32x4 s1 = (f32x4){0.f, 0.f, 0.f, 0.f};
#pragma unroll
        for (int ck = 0; ck < 8; ++ck) {
            int q = ck * 4 + gq;
            bf16x8 k0 = *(const bf16x8*)(kt + l16 * 256 + ((q ^ (l16 & 7)) << 3));
            s0 = __builtin_amdgcn_mfma_f32_16x16x32_bf16(qf[ck], k0, s0, 0, 0, 0);
            int row1 = 16 + l16;
            bf16x8 k1 = *(const bf16x8*)(kt + row1 * 256 + ((q ^ (row1 & 7)) << 3));
            s1 = __builtin_amdgcn_mfma_f32_16x16x32_bf16(qf[ck], k1, s1, 0, 0, 0);
        }

        // online softmax; D: row i = gq*4+r, col j = l16 (+16 for s1)
        float vmax[4];
#pragma unroll
        for (int r = 0; r < 4; ++r) {
            float v = fmaxf(s0[r], s1[r]);
            v = fmaxf(v, __shfl_xor(v, 1));
            v = fmaxf(v, __shfl_xor(v, 2));
            v = fmaxf(v, __shfl_xor(v, 4));
            v = fmaxf(v, __shfl_xor(v, 8));
            vmax[r] = v;
        }
        bool grow = (vmax[0] > m_run[0]) || (vmax[1] > m_run[1]) ||
                    (vmax[2] > m_run[2]) || (vmax[3] > m_run[3]);
        if (__any((int)grow)) {                  // exact skip: only rescale when a max grew
#pragma unroll
            for (int r = 0; r < 4; ++r) {
                float nm = fmaxf(m_run[r], vmax[r]);
                float sc = __expf(m_run[r] - nm);
                m_run[r] = nm;
                l_run[r] *= sc;
#pragma unroll
                for (int cf = 0; cf < 16; ++cf) acc[cf][r] *= sc;
            }
        }
        float p0[4], p1[4];
#pragma unroll
        for (int r = 0; r < 4; ++r) {
            p0[r] = __expf(s0[r] - m_run[r]);
            p1[r] = __expf(s1[r] - m_run[r]);
            float v = p0[r] + p1[r];
            v += __shfl_xor(v, 1);
            v += __shfl_xor(v, 2);
            v += __shfl_xor(v, 4);
            v += __shfl_xor(v, 8);
            l_run[r] += v;
        }

        // P -> wave-private LDS strip (swizzled), then read back as A-fragment
        __bf16* myP = &sP[w][0];
#pragma unroll
        for (int r = 0; r < 4; ++r) {
            int i = gq * 4 + r;
            int key = (i >> 1) & 3;
            myP[i * 32 + (((l16 >> 3) ^ key) << 3) + (l16 & 7)] = (__bf16)p0[r];
            int j1 = 16 + l16;
            myP[i * 32 + (((j1 >> 3) ^ key) << 3) + (j1 & 7)] = (__bf16)p1[r];
        }
        bf16x8 pa = *(const bf16x8*)(&myP[l16 * 32 + ((gq ^ ((l16 >> 1) & 3)) << 3)]);

        // O += P V   (B-fragments from registers)
#pragma unroll
        for (int cf = 0; cf < 16; ++cf)
            acc[cf] = __builtin_amdgcn_mfma_f32_16x16x32_bf16(pa, vv[cf], acc[cf], 0, 0, 0);

        __syncthreads();   // all waves done with buf[cur]; next-tile gl_lds drained here
        cur ^= 1;
    }

    // ---- merge the two j-halves (waves w and w+2 share a q-strip) ----
    if (l16 == 0) {
#pragma unroll
        for (int r = 0; r < 4; ++r) {
            sML[w][gq * 4 + r][0] = m_run[r];
            sML[w][gq * 4 + r][1] = l_run[r];
        }
    }
    if (w >= 2) {
        float* F = ((float*)&sK[0][0][0]) + (size_t)(w - 2) * 4096;  // 16KB strip in dead K buffers
#pragma unroll
        for (int cf = 0; cf < 16; ++cf)
#pragma unroll
            for (int r = 0; r < 4; ++r)
                F[cf * 256 + (gq * 4 + r) * 16 + l16] = acc[cf][r];
    }
    __syncthreads();
    if (w < 2) {
        const float* F = ((float*)&sK[0][0][0]) + (size_t)w * 4096;
        float sA[4], sB[4], inv[4];
#pragma unroll
        for (int r = 0; r < 4; ++r) {
            int i = gq * 4 + r;
            float mA = m_run[r], lA = l_run[r];
            float mB = sML[w + 2][i][0], lB = sML[w + 2][i][1];
            float m = fmaxf(mA, mB);
            float eA = __expf(mA - m), eB = __expf(mB - m);
            sA[r] = eA; sB[r] = eB;
            inv[r] = 1.f / (lA * eA + lB * eB);
        }
        // wave-private transpose buffer in the (dead) P region; stores coalesced along n
        float* sT = ((float*)&sP[0][0]) + (size_t)w * 288;  // 272 used, 288 stride
#pragma unroll
        for (int cf = 0; cf < 16; ++cf) {
#pragma unroll
            for (int r = 0; r < 4; ++r) {
                float o = (acc[cf][r] * sA[r] +
                           F[cf * 256 + (gq * 4 + r) * 16 + l16] * sB[r]) * inv[r];
                sT[(gq * 4 + r) * 17 + l16] = o;
            }
#pragma unroll
            for (int r = 0; r < 4; ++r) {
                int c = cf * 16 + gq + r * 4;
                out[((size_t)(b * NC + c)) * NN + i_base + l16] = sT[l16 * 17 + gq + r * 4];
            }
        }
    }
}

extern "C" void kernel_launch(void* const* d_in, const int* in_sizes, int n_in,
                              void* d_out, int out_size, void* d_ws, size_t ws_size,
                              hipStream_t stream) {
    const float* x = (const float*)d_in[0];
    float* out = (float*)d_out;
    __bf16* xt = (__bf16*)d_ws;                       // [4][4096][256] bf16 = 8 MiB
    __bf16* xc = xt + (size_t)NB * NN * NC;           // [4][256][4096] bf16 = 8 MiB

    prep_kernel<<<dim3(NN / 64, NC / 64, NB), dim3(256), 0, stream>>>(x, xt, xc);
    flash_kernel<<<dim3(512), dim3(256), 0, stream>>>(xt, xc, out);
}

// Round 7
// 246.112 us; speedup vs baseline: 1.3625x; 1.3625x over previous
//
#include <hip/hip_runtime.h>
#include <hip/hip_bf16.h>

typedef __bf16 bf16x8 __attribute__((ext_vector_type(8)));
typedef float f32x4 __attribute__((ext_vector_type(4)));

#define NB 4
#define NC 256
#define NN 4096
#define BK 32
#define NT 64   // tiles per j-group: 2 groups * 64 tiles * BK = 4096

__device__ __forceinline__ void stage16(const void* g, void* l) {
    __builtin_amdgcn_global_load_lds(
        (const __attribute__((address_space(1))) unsigned int*)g,
        (__attribute__((address_space(3))) unsigned int*)l, 16, 0, 0);
}

// ---------- prep: x fp32 [b][c][n] -> xt bf16 [b][n][c] (transposed),
//                                      xv bf16 [b][tile(128)][c(256)][j(32)] (tile-major V^T) ----------
__global__ __launch_bounds__(256) void prep_kernel(const float* __restrict__ x,
                                                   __bf16* __restrict__ xt,
                                                   __bf16* __restrict__ xv) {
    __shared__ __align__(16) __bf16 tile[64 * 64];  // swizzled 16B chunks, no pad
    const int b = blockIdx.z, c0 = blockIdx.y * 64, n0 = blockIdx.x * 64;
    const int t = threadIdx.x;
    {
        const int cc = t >> 2, nch = (t & 3) << 4;   // 16 floats per thread
        const float* src = x + ((size_t)(b * NC + c0 + cc)) * NN + n0 + nch;
        f32x4 v[4];
        v[0] = *(const f32x4*)(src);
        v[1] = *(const f32x4*)(src + 4);
        v[2] = *(const f32x4*)(src + 8);
        v[3] = *(const f32x4*)(src + 12);
        bf16x8 o[2];
#pragma unroll
        for (int q = 0; q < 2; ++q)
#pragma unroll
            for (int k = 0; k < 8; ++k)
                o[q][k] = (__bf16)v[q * 2 + (k >> 2)][k & 3];
        // V^T tile-major write: tile = (n0+nch)/32, row c, j-offset = nch&31
        const int tile_idx = (n0 + nch) >> 5;
        const int off_j = nch & 31;                  // 0 or 16
        __bf16* dstv = xv + (((size_t)(b * (NN / 32) + tile_idx)) * NC + (c0 + cc)) * 32 + off_j;
        *(bf16x8*)(dstv) = o[0];
        *(bf16x8*)(dstv + 8) = o[1];
        const int key = (cc ^ (cc >> 3)) & 7;        // rows 16 apart get distinct keys
#pragma unroll
        for (int q = 0; q < 2; ++q) {
            int nc = (nch >> 3) + q;
            *(bf16x8*)(&tile[cc * 64 + ((nc ^ key) << 3)]) = o[q];
        }
    }
    __syncthreads();
    {
        const int nn = t >> 2, cch = (t & 3) << 4;
        bf16x8 o[2];
#pragma unroll
        for (int k = 0; k < 16; ++k) {
            int r = cch + k;
            int key = (r ^ (r >> 3)) & 7;
            o[k >> 3][k & 7] = tile[r * 64 + (((nn >> 3) ^ key) << 3) + (nn & 7)];
        }
        __bf16* dst = xt + ((size_t)(b * NN + n0 + nn)) * NC + c0 + cch;
        *(bf16x8*)(dst) = o[0];
        *(bf16x8*)(dst + 8) = o[1];
    }
}

// ---------- flash attention: 512 blocks (2/CU), 4 waves = 2 KV-groups x 2 q-strips ----------
__global__ __launch_bounds__(256, 2) void flash_kernel(const __bf16* __restrict__ xt,
                                                       const __bf16* __restrict__ xv,
                                                       float* __restrict__ out) {
    __shared__ __align__(16) __bf16 sK[2][2][BK * NC];  // [group][buf][32 j][256 c] 64KB
    __shared__ __align__(16) __bf16 sP[4][16 * BK];     // per-wave P strip, 4KB
    __shared__ float sML[4][16][2];                     // m,l exchange

    const int bid = blockIdx.x;
    const int xcd = bid & 7;
    const int b = xcd >> 1;                          // batch -> XCD pair; 4MB/batch = L2/XCD
    const int qblk = ((bid >> 3) << 1) | (xcd & 1);  // 0..127

    const int tid = threadIdx.x;
    const int w = tid >> 6;        // wave 0..3
    const int grp = w >> 1;        // 0: tiles 0..63, 1: tiles 64..127
    const int wg = w & 1;          // q-strip
    const int lane = tid & 63;
    const int l16 = lane & 15;
    const int gq = lane >> 4;

    const int i_base = qblk * 32 + wg * 16;

    const char* xtb = (const char*)(xt + (size_t)b * NN * NC);
    const __bf16* vb0 = xv + (size_t)(b * (NN / 32)) * (NC * BK);

    // Q fragments in registers: A[i=l16][k = gq*8+e + 32*ck]
    bf16x8 qf[8];
    {
        const __bf16* qrow = (const __bf16*)xtb + (size_t)(i_base + l16) * NC + gq * 8;
#pragma unroll
        for (int ck = 0; ck < 8; ++ck) qf[ck] = *(const bf16x8*)(qrow + ck * 32);
    }

    f32x4 acc[16];
#pragma unroll
    for (int cf = 0; cf < 16; ++cf) acc[cf] = (f32x4){0.f, 0.f, 0.f, 0.f};
    float m_run[4], l_run[4];
#pragma unroll
    for (int r = 0; r < 4; ++r) { m_run[r] = -3.0e38f; l_run[r] = 0.f; }

    // stage K tile t of this wave's group into buffer bf (linear LDS dest,
    // swizzle applied by permuting the GLOBAL source chunk - rule #21)
    auto stage = [&](int bf, int t) {
        const int tj = grp * NT + t;
        const char* kb = xtb + (size_t)tj * BK * (NC * 2);
        __bf16* dk = &sK[grp][bf][0];
#pragma unroll
        for (int q = 0; q < 8; ++q) {
            int ci = wg * 8 + q;                 // 1KB chunk = 2 K-rows
            int rl = ci * 2 + (lane >> 5);
            int cs = (lane & 31) ^ (rl & 7);     // inverse of read swizzle
            stage16(kb + rl * 512 + cs * 16, dk + ci * 512);
        }
    };

    stage(0, 0);
    __syncthreads();
    int cur = 0;

    for (int t = 0; t < NT; ++t) {
        // V fragments from tile-major xv FIRST (so the pre-PV wait is a counted
        // vmcnt that leaves the K-prefetch below in flight - T4)
        const __bf16* vtile = vb0 + (size_t)(grp * NT + t) * (NC * BK);
        bf16x8 vv[16];
#pragma unroll
        for (int cf = 0; cf < 16; ++cf)
            vv[cf] = *(const bf16x8*)(vtile + (cf * 16 + l16) * BK + gq * 8);

        if (t + 1 < NT) stage(cur ^ 1, t + 1);   // issue-early; drains at the barrier below

        const __bf16* kt = &sK[grp][cur][0];

        // S = Q K^T  (two 16-col fragments cover BK=32)
        f32x4 s0 = (f32x4){0.f, 0.f, 0.f, 0.f};
        f32x4 s1 = (f32x4){0.f, 0.f, 0.f, 0.f};
#pragma unroll
        for (int ck = 0; ck < 8; ++ck) {
            int q = ck * 4 + gq;
            bf16x8 k0 = *(const bf16x8*)(kt + l16 * 256 + ((q ^ (l16 & 7)) << 3));
            s0 = __builtin_amdgcn_mfma_f32_16x16x32_bf16(qf[ck], k0, s0, 0, 0, 0);
            int row1 = 16 + l16;
            bf16x8 k1 = *(const bf16x8*)(kt + row1 * 256 + ((q ^ (row1 & 7)) << 3));
            s1 = __builtin_amdgcn_mfma_f32_16x16x32_bf16(qf[ck], k1, s1, 0, 0, 0);
        }

        // online softmax; D: row i = gq*4+r, col j = l16 (+16 for s1)
        float vmax[4];
#pragma unroll
        for (int r = 0; r < 4; ++r) {
            float v = fmaxf(s0[r], s1[r]);
            v = fmaxf(v, __shfl_xor(v, 1));
            v = fmaxf(v, __shfl_xor(v, 2));
            v = fmaxf(v, __shfl_xor(v, 4));
            v = fmaxf(v, __shfl_xor(v, 8));
            vmax[r] = v;
        }
        bool grow = (vmax[0] > m_run[0]) || (vmax[1] > m_run[1]) ||
                    (vmax[2] > m_run[2]) || (vmax[3] > m_run[3]);
        if (__any((int)grow)) {                  // exact skip: only rescale when a max grew
#pragma unroll
            for (int r = 0; r < 4; ++r) {
                float nm = fmaxf(m_run[r], vmax[r]);
                float sc = __expf(m_run[r] - nm);
                m_run[r] = nm;
                l_run[r] *= sc;
#pragma unroll
                for (int cf = 0; cf < 16; ++cf) acc[cf][r] *= sc;
            }
        }
        float p0[4], p1[4];
#pragma unroll
        for (int r = 0; r < 4; ++r) {
            p0[r] = __expf(s0[r] - m_run[r]);
            p1[r] = __expf(s1[r] - m_run[r]);
            float v = p0[r] + p1[r];
            v += __shfl_xor(v, 1);
            v += __shfl_xor(v, 2);
            v += __shfl_xor(v, 4);
            v += __shfl_xor(v, 8);
            l_run[r] += v;
        }

        // P -> wave-private LDS strip (swizzled), then read back as A-fragment
        __bf16* myP = &sP[w][0];
#pragma unroll
        for (int r = 0; r < 4; ++r) {
            int i = gq * 4 + r;
            int key = (i >> 1) & 3;
            myP[i * 32 + (((l16 >> 3) ^ key) << 3) + (l16 & 7)] = (__bf16)p0[r];
            int j1 = 16 + l16;
            myP[i * 32 + (((j1 >> 3) ^ key) << 3) + (j1 & 7)] = (__bf16)p1[r];
        }
        bf16x8 pa = *(const bf16x8*)(&myP[l16 * 32 + ((gq ^ ((l16 >> 1) & 3)) << 3)]);

        // O += P V   (B-fragments from registers; wait here = counted vmcnt, K-prefetch stays live)
#pragma unroll
        for (int cf = 0; cf < 16; ++cf)
            acc[cf] = __builtin_amdgcn_mfma_f32_16x16x32_bf16(pa, vv[cf], acc[cf], 0, 0, 0);

        __syncthreads();   // all waves done with buf[cur]; next-tile gl_lds drained here
        cur ^= 1;
    }

    // ---- merge the two j-halves (waves w and w+2 share a q-strip) ----
    if (l16 == 0) {
#pragma unroll
        for (int r = 0; r < 4; ++r) {
            sML[w][gq * 4 + r][0] = m_run[r];
            sML[w][gq * 4 + r][1] = l_run[r];
        }
    }
    if (w >= 2) {
        float* F = ((float*)&sK[0][0][0]) + (size_t)(w - 2) * 4096;  // 16KB strip in dead K buffers
#pragma unroll
        for (int cf = 0; cf < 16; ++cf)
#pragma unroll
            for (int r = 0; r < 4; ++r)
                F[cf * 256 + (gq * 4 + r) * 16 + l16] = acc[cf][r];
    }
    __syncthreads();
    if (w < 2) {
        const float* F = ((float*)&sK[0][0][0]) + (size_t)w * 4096;
        float sA[4], sB[4], inv[4];
#pragma unroll
        for (int r = 0; r < 4; ++r) {
            int i = gq * 4 + r;
            float mA = m_run[r], lA = l_run[r];
            float mB = sML[w + 2][i][0], lB = sML[w + 2][i][1];
            float m = fmaxf(mA, mB);
            float eA = __expf(mA - m), eB = __expf(mB - m);
            sA[r] = eA; sB[r] = eB;
            inv[r] = 1.f / (lA * eA + lB * eB);
        }
        // wave-private transpose buffer in the (dead) P region; stores coalesced along n
        float* sT = ((float*)&sP[0][0]) + (size_t)w * 288;  // 272 used, 288 stride
#pragma unroll
        for (int cf = 0; cf < 16; ++cf) {
#pragma unroll
            for (int r = 0; r < 4; ++r) {
                float o = (acc[cf][r] * sA[r] +
                           F[cf * 256 + (gq * 4 + r) * 16 + l16] * sB[r]) * inv[r];
                sT[(gq * 4 + r) * 17 + l16] = o;
            }
#pragma unroll
            for (int r = 0; r < 4; ++r) {
                int c = cf * 16 + gq + r * 4;
                out[((size_t)(b * NC + c)) * NN + i_base + l16] = sT[l16 * 17 + gq + r * 4];
            }
        }
    }
}

extern "C" void kernel_launch(void* const* d_in, const int* in_sizes, int n_in,
                              void* d_out, int out_size, void* d_ws, size_t ws_size,
                              hipStream_t stream) {
    const float* x = (const float*)d_in[0];
    float* out = (float*)d_out;
    __bf16* xt = (__bf16*)d_ws;                       // [4][4096][256] bf16 = 8 MiB
    __bf16* xv = xt + (size_t)NB * NN * NC;           // [4][128][256][32] bf16 = 8 MiB

    prep_kernel<<<dim3(NN / 64, NC / 64, NB), dim3(256), 0, stream>>>(x, xt, xv);
    flash_kernel<<<dim3(512), dim3(256), 0, stream>>>(xt, xv, out);
}

// Round 8
// 223.926 us; speedup vs baseline: 1.4975x; 1.0991x over previous
//
#include <hip/hip_runtime.h>
#include <hip/hip_bf16.h>

typedef __bf16 bf16x8 __attribute__((ext_vector_type(8)));
typedef float f32x4 __attribute__((ext_vector_type(4)));

#define NB 4
#define NC 256
#define NN 4096
#define BK 32
#define NT 64   // tiles per j-group: 2 groups * 64 tiles * BK = 4096

__device__ __forceinline__ void stage16(const void* g, void* l) {
    __builtin_amdgcn_global_load_lds(
        (const __attribute__((address_space(1))) unsigned int*)g,
        (__attribute__((address_space(3))) unsigned int*)l, 16, 0, 0);
}

// VALU-pipe cross-lane: DPP row_ror within each 16-lane row (no DS-pipe traffic)
template <int CTRL>
__device__ __forceinline__ float fdpp(float x) {
    return __int_as_float(__builtin_amdgcn_update_dpp(
        __float_as_int(x), __float_as_int(x), CTRL, 0xF, 0xF, false));
}
__device__ __forceinline__ float dpp_max16(float v) {
    v = fmaxf(v, fdpp<0x121>(v));   // row_ror:1
    v = fmaxf(v, fdpp<0x122>(v));   // row_ror:2
    v = fmaxf(v, fdpp<0x124>(v));   // row_ror:4
    v = fmaxf(v, fdpp<0x128>(v));   // row_ror:8
    return v;
}
__device__ __forceinline__ float dpp_sum16(float v) {
    v += fdpp<0x121>(v);
    v += fdpp<0x122>(v);
    v += fdpp<0x124>(v);
    v += fdpp<0x128>(v);
    return v;
}

// ---------- prep: x fp32 [b][c][n] -> xt bf16 [b][n][c] (transposed),
//                                      xv bf16 [b][tile(128)][c(256)][j(32)] (tile-major V^T) ----------
__global__ __launch_bounds__(256) void prep_kernel(const float* __restrict__ x,
                                                   __bf16* __restrict__ xt,
                                                   __bf16* __restrict__ xv) {
    __shared__ __align__(16) __bf16 tile[64 * 64];  // swizzled 16B chunks, no pad
    const int b = blockIdx.z, c0 = blockIdx.y * 64, n0 = blockIdx.x * 64;
    const int t = threadIdx.x;
    {
        const int cc = t >> 2, nch = (t & 3) << 4;   // 16 floats per thread
        const float* src = x + ((size_t)(b * NC + c0 + cc)) * NN + n0 + nch;
        f32x4 v[4];
        v[0] = *(const f32x4*)(src);
        v[1] = *(const f32x4*)(src + 4);
        v[2] = *(const f32x4*)(src + 8);
        v[3] = *(const f32x4*)(src + 12);
        bf16x8 o[2];
#pragma unroll
        for (int q = 0; q < 2; ++q)
#pragma unroll
            for (int k = 0; k < 8; ++k)
                o[q][k] = (__bf16)v[q * 2 + (k >> 2)][k & 3];
        // V^T tile-major write: tile = (n0+nch)/32, row c, j-offset = nch&31
        const int tile_idx = (n0 + nch) >> 5;
        const int off_j = nch & 31;                  // 0 or 16
        __bf16* dstv = xv + (((size_t)(b * (NN / 32) + tile_idx)) * NC + (c0 + cc)) * 32 + off_j;
        *(bf16x8*)(dstv) = o[0];
        *(bf16x8*)(dstv + 8) = o[1];
        const int key = (cc ^ (cc >> 3)) & 7;        // rows 16 apart get distinct keys
#pragma unroll
        for (int q = 0; q < 2; ++q) {
            int nc = (nch >> 3) + q;
            *(bf16x8*)(&tile[cc * 64 + ((nc ^ key) << 3)]) = o[q];
        }
    }
    __syncthreads();
    {
        const int nn = t >> 2, cch = (t & 3) << 4;
        bf16x8 o[2];
#pragma unroll
        for (int k = 0; k < 16; ++k) {
            int r = cch + k;
            int key = (r ^ (r >> 3)) & 7;
            o[k >> 3][k & 7] = tile[r * 64 + (((nn >> 3) ^ key) << 3) + (nn & 7)];
        }
        __bf16* dst = xt + ((size_t)(b * NN + n0 + nn)) * NC + c0 + cch;
        *(bf16x8*)(dst) = o[0];
        *(bf16x8*)(dst + 8) = o[1];
    }
}

// ---------- flash attention: 512 blocks (2/CU), 4 waves = 2 KV-groups x 2 q-strips ----------
__global__ __launch_bounds__(256, 2) void flash_kernel(const __bf16* __restrict__ xt,
                                                       const __bf16* __restrict__ xv,
                                                       float* __restrict__ out) {
    __shared__ __align__(16) __bf16 sK[2][2][BK * NC];  // [group][buf][32 j][256 c] 64KB
    __shared__ __align__(16) __bf16 sP[4][16 * BK];     // per-wave P strip, 4KB
    __shared__ float sML[4][16][2];                     // m,l exchange

    const int bid = blockIdx.x;
    const int xcd = bid & 7;
    const int b = xcd >> 1;                          // batch -> XCD pair; 4MB/batch = L2/XCD
    const int qblk = ((bid >> 3) << 1) | (xcd & 1);  // 0..127

    const int tid = threadIdx.x;
    const int w = tid >> 6;        // wave 0..3
    const int grp = w >> 1;        // 0: tiles 0..63, 1: tiles 64..127
    const int wg = w & 1;          // q-strip
    const int lane = tid & 63;
    const int l16 = lane & 15;
    const int gq = lane >> 4;

    const int i_base = qblk * 32 + wg * 16;

    const char* xtb = (const char*)(xt + (size_t)b * NN * NC);
    const __bf16* vb0 = xv + (size_t)(b * (NN / 32)) * (NC * BK);

    // Q fragments in registers: A[i=l16][k = gq*8+e + 32*ck]
    bf16x8 qf[8];
    {
        const __bf16* qrow = (const __bf16*)xtb + (size_t)(i_base + l16) * NC + gq * 8;
#pragma unroll
        for (int ck = 0; ck < 8; ++ck) qf[ck] = *(const bf16x8*)(qrow + ck * 32);
    }

    f32x4 acc[16];
#pragma unroll
    for (int cf = 0; cf < 16; ++cf) acc[cf] = (f32x4){0.f, 0.f, 0.f, 0.f};
    float m_run[4], l_part[4];
#pragma unroll
    for (int r = 0; r < 4; ++r) { m_run[r] = -3.0e38f; l_part[r] = 0.f; }

    // stage K tile t of this wave's group into buffer bf (linear LDS dest,
    // swizzle applied by permuting the GLOBAL source chunk - rule #21)
    auto stage = [&](int bf, int t) {
        const int tj = grp * NT + t;
        const char* kb = xtb + (size_t)tj * BK * (NC * 2);
        __bf16* dk = &sK[grp][bf][0];
#pragma unroll
        for (int q = 0; q < 8; ++q) {
            int ci = wg * 8 + q;                 // 1KB chunk = 2 K-rows
            int rl = ci * 2 + (lane >> 5);
            int cs = (lane & 31) ^ (rl & 7);     // inverse of read swizzle
            stage16(kb + rl * 512 + cs * 16, dk + ci * 512);
        }
    };

    stage(0, 0);
    __syncthreads();
    int cur = 0;

    for (int t = 0; t < NT; ++t) {
        // V fragments from tile-major xv FIRST (counted vmcnt leaves K-prefetch live - T4)
        const __bf16* vtile = vb0 + (size_t)(grp * NT + t) * (NC * BK);
        bf16x8 vv[16];
#pragma unroll
        for (int cf = 0; cf < 16; ++cf)
            vv[cf] = *(const bf16x8*)(vtile + (cf * 16 + l16) * BK + gq * 8);

        if (t + 1 < NT) stage(cur ^ 1, t + 1);   // issue-early; drains at the barrier below

        const __bf16* kt = &sK[grp][cur][0];

        // S = Q K^T  (two 16-col fragments cover BK=32)
        f32x4 s0 = (f32x4){0.f, 0.f, 0.f, 0.f};
        f32x4 s1 = (f32x4){0.f, 0.f, 0.f, 0.f};
#pragma unroll
        for (int ck = 0; ck < 8; ++ck) {
            int q = ck * 4 + gq;
            bf16x8 k0 = *(const bf16x8*)(kt + l16 * 256 + ((q ^ (l16 & 7)) << 3));
            s0 = __builtin_amdgcn_mfma_f32_16x16x32_bf16(qf[ck], k0, s0, 0, 0, 0);
            int row1 = 16 + l16;
            bf16x8 k1 = *(const bf16x8*)(kt + row1 * 256 + ((q ^ (row1 & 7)) << 3));
            s1 = __builtin_amdgcn_mfma_f32_16x16x32_bf16(qf[ck], k1, s1, 0, 0, 0);
        }

        // ---- softmax, no per-iter cross-lane work (exact deferred max) ----
        // D layout: row i = gq*4+r, col j = l16 (+16 for s1)
        float tmax[4];
        bool cond = false;
#pragma unroll
        for (int r = 0; r < 4; ++r) {
            tmax[r] = fmaxf(s0[r], s1[r]);
            cond |= (tmax[r] > m_run[r]);
        }
        if (__any((int)cond)) {   // rare: ~ln(NT)+diag-tile of 64 iters; VALU-pipe DPP reduce
#pragma unroll
            for (int r = 0; r < 4; ++r) {
                float v = dpp_max16(tmax[r]);
                float nm = fmaxf(m_run[r], v);
                float sc = __expf(m_run[r] - nm);
                m_run[r] = nm;
                l_part[r] *= sc;
#pragma unroll
                for (int cf = 0; cf < 16; ++cf) acc[cf][r] *= sc;
            }
        }
        float p0[4], p1[4];
#pragma unroll
        for (int r = 0; r < 4; ++r) {
            p0[r] = __expf(s0[r] - m_run[r]);
            p1[r] = __expf(s1[r] - m_run[r]);
            l_part[r] += p0[r] + p1[r];     // lane-local partial sum; reduced once at end
        }

        // P -> wave-private LDS strip (swizzled), then read back as A-fragment
        __bf16* myP = &sP[w][0];
#pragma unroll
        for (int r = 0; r < 4; ++r) {
            int i = gq * 4 + r;
            int key = (i >> 1) & 3;
            myP[i * 32 + (((l16 >> 3) ^ key) << 3) + (l16 & 7)] = (__bf16)p0[r];
            int j1 = 16 + l16;
            myP[i * 32 + (((j1 >> 3) ^ key) << 3) + (j1 & 7)] = (__bf16)p1[r];
        }
        bf16x8 pa = *(const bf16x8*)(&myP[l16 * 32 + ((gq ^ ((l16 >> 1) & 3)) << 3)]);

        // O += P V   (B-fragments from registers)
#pragma unroll
        for (int cf = 0; cf < 16; ++cf)
            acc[cf] = __builtin_amdgcn_mfma_f32_16x16x32_bf16(pa, vv[cf], acc[cf], 0, 0, 0);

        __syncthreads();   // all waves done with buf[cur]; next-tile gl_lds drained here
        cur ^= 1;
    }

    // final 16-lane sum of the partial l (VALU DPP, once)
    float l_run[4];
#pragma unroll
    for (int r = 0; r < 4; ++r) l_run[r] = dpp_sum16(l_part[r]);

    // ---- merge the two j-halves (waves w and w+2 share a q-strip) ----
    if (l16 == 0) {
#pragma unroll
        for (int r = 0; r < 4; ++r) {
            sML[w][gq * 4 + r][0] = m_run[r];
            sML[w][gq * 4 + r][1] = l_run[r];
        }
    }
    if (w >= 2) {
        float* F = ((float*)&sK[0][0][0]) + (size_t)(w - 2) * 4096;  // 16KB strip in dead K buffers
#pragma unroll
        for (int cf = 0; cf < 16; ++cf)
#pragma unroll
            for (int r = 0; r < 4; ++r)
                F[cf * 256 + (gq * 4 + r) * 16 + l16] = acc[cf][r];
    }
    __syncthreads();
    if (w < 2) {
        const float* F = ((float*)&sK[0][0][0]) + (size_t)w * 4096;
        float sA[4], sB[4], inv[4];
#pragma unroll
        for (int r = 0; r < 4; ++r) {
            int i = gq * 4 + r;
            float mA = m_run[r], lA = l_run[r];
            float mB = sML[w + 2][i][0], lB = sML[w + 2][i][1];
            float m = fmaxf(mA, mB);
            float eA = __expf(mA - m), eB = __expf(mB - m);
            sA[r] = eA; sB[r] = eB;
            inv[r] = 1.f / (lA * eA + lB * eB);
        }
        // wave-private transpose buffer in the (dead) P region; stores coalesced along n
        float* sT = ((float*)&sP[0][0]) + (size_t)w * 288;  // 272 used, 288 stride
#pragma unroll
        for (int cf = 0; cf < 16; ++cf) {
#pragma unroll
            for (int r = 0; r < 4; ++r) {
                float o = (acc[cf][r] * sA[r] +
                           F[cf * 256 + (gq * 4 + r) * 16 + l16] * sB[r]) * inv[r];
                sT[(gq * 4 + r) * 17 + l16] = o;
            }
#pragma unroll
            for (int r = 0; r < 4; ++r) {
                int c = cf * 16 + gq + r * 4;
                out[((size_t)(b * NC + c)) * NN + i_base + l16] = sT[l16 * 17 + gq + r * 4];
            }
        }
    }
}

extern "C" void kernel_launch(void* const* d_in, const int* in_sizes, int n_in,
                              void* d_out, int out_size, void* d_ws, size_t ws_size,
                              hipStream_t stream) {
    const float* x = (const float*)d_in[0];
    float* out = (float*)d_out;
    __bf16* xt = (__bf16*)d_ws;                       // [4][4096][256] bf16 = 8 MiB
    __bf16* xv = xt + (size_t)NB * NN * NC;           // [4][128][256][32] bf16 = 8 MiB

    prep_kernel<<<dim3(NN / 64, NC / 64, NB), dim3(256), 0, stream>>>(x, xt, xv);
    flash_kernel<<<dim3(512), dim3(256), 0, stream>>>(xt, xv, out);
}